// Round 6
// baseline (340.525 us; speedup 1.0000x reference)
//
#include <hip/hip_runtime.h>
#include <math.h>

#define BATCH 8
#define CH    256
#define HWPIX 4096
#define CQK_  32

typedef __bf16 bf16x8 __attribute__((ext_vector_type(8)));
typedef __bf16 bf16x4 __attribute__((ext_vector_type(4)));
typedef __bf16 bf16x2 __attribute__((ext_vector_type(2)));
typedef float  f32x4  __attribute__((ext_vector_type(4)));

#define FS_STR 68   // LDS transpose-tile row stride in bf16 (136 B: 8B-aligned)

// load a bf16x8 fragment from LDS as two 8B halves (rows only 8B-aligned)
static __device__ inline bf16x8 ld_frag(const __bf16* p) {
  bf16x4 lo = *(const bf16x4*)p;
  bf16x4 hi = *(const bf16x4*)(p + 4);
  return __builtin_shufflevector(lo, hi, 0, 1, 2, 3, 4, 5, 6, 7);
}

// load 8 consecutive fp32 from a W row, convert to bf16x8 fragment
static __device__ inline bf16x8 w_frag(const float* p) {
  const float4 a = *(const float4*)p;
  const float4 b = *(const float4*)(p + 4);
  bf16x8 r;
  r[0] = (__bf16)a.x; r[1] = (__bf16)a.y; r[2] = (__bf16)a.z; r[3] = (__bf16)a.w;
  r[4] = (__bf16)b.x; r[5] = (__bf16)b.y; r[6] = (__bf16)b.z; r[7] = (__bf16)b.w;
  return r;
}

// ---- Fused projections (FROZEN from R4 — measurement target this round).
// grid (64 n-tiles, 3 modes, 8 b), block 256 = 4 waves.
// mode 0: Q -> qT[b][n][32] AND K -> kT[b][n][32] (both staged)
// mode 1,2: V c-half (mode-1)*128 -> vv[b][c][hw]
__global__ __launch_bounds__(256, 4) void proj_all(
    const float* __restrict__ f1, const float* __restrict__ f2,
    const float* __restrict__ f3,
    const float* __restrict__ wq, const float* __restrict__ bq,
    const float* __restrict__ wk, const float* __restrict__ bk,
    const float* __restrict__ wv, const float* __restrict__ bv,
    __bf16* __restrict__ qT, __bf16* __restrict__ kT, __bf16* __restrict__ vv)
{
  __shared__ __align__(16) __bf16 f_s[2][64 * FS_STR];  // [n][cin] transposed tiles
  const int t    = threadIdx.x;
  const int w    = __builtin_amdgcn_readfirstlane(t >> 6);
  const int lane = t & 63;
  const int q16  = lane & 15;
  const int quad = lane >> 4;
  const int b    = blockIdx.z;
  const int n0   = blockIdx.x * 64;
  const int mode = blockIdx.y;

  // staging helpers: f[c0..+64)[n0..+64) -> regs -> dst[n][cin] bf16 (transposed)
  const int sn  = (t & 15) * 4;
  const int scp = (t >> 4) * 2;
#define STAGE_LOAD(fb, c0, reg)                                                  \
  {                                                                              \
    _Pragma("unroll") for (int rr = 0; rr < 2; ++rr) {                           \
      const int c = rr * 32 + scp;                                               \
      reg[2 * rr + 0] = *(const float4*)&(fb)[(size_t)((c0) + c) * HWPIX + sn];  \
      reg[2 * rr + 1] = *(const float4*)&(fb)[(size_t)((c0) + c + 1) * HWPIX + sn]; \
    }                                                                            \
  }
#define STAGE_WRITE(reg, dst)                                                    \
  {                                                                              \
    _Pragma("unroll") for (int rr = 0; rr < 2; ++rr) {                           \
      const int c = rr * 32 + scp;                                               \
      _Pragma("unroll") for (int i = 0; i < 4; ++i) {                            \
        bf16x2 pk;                                                               \
        pk[0] = (__bf16)((const float*)&reg[2 * rr + 0])[i];                     \
        pk[1] = (__bf16)((const float*)&reg[2 * rr + 1])[i];                     \
        *(bf16x2*)&(dst)[(sn + i) * FS_STR + c] = pk;                            \
      }                                                                          \
    }                                                                            \
  }

  if (mode == 0) {
    const float* f1b = f1 + (size_t)b * CH * HWPIX + n0;
    const float* f2b = f2 + (size_t)b * CH * HWPIX + n0;
    f32x4 accQ[2], accK[2];
#pragma unroll
    for (int i = 0; i < 2; ++i) {
      accQ[i] = (f32x4){0.f, 0.f, 0.f, 0.f};
      accK[i] = (f32x4){0.f, 0.f, 0.f, 0.f};
    }
    float4 rQ[4], rK[4];
    STAGE_LOAD(f1b, 0, rQ);
    STAGE_LOAD(f2b, 0, rK);
    for (int c0 = 0; c0 < CH; c0 += 64) {
      __syncthreads();  // previous iter's readers done; LDS reusable
      STAGE_WRITE(rQ, f_s[0]);
      STAGE_WRITE(rK, f_s[1]);
      __syncthreads();
      if (c0 < CH - 64) {  // prefetch next tile; latency hidden under compute
        STAGE_LOAD(f1b, c0 + 64, rQ);
        STAGE_LOAD(f2b, c0 + 64, rK);
      }
      bf16x8 afQ[2], afK[2];
#pragma unroll
      for (int kh = 0; kh < 2; ++kh) {
        afQ[kh] = ld_frag(&f_s[0][(16 * w + q16) * FS_STR + 32 * kh + quad * 8]);
        afK[kh] = ld_frag(&f_s[1][(16 * w + q16) * FS_STR + 32 * kh + quad * 8]);
      }
#pragma unroll
      for (int ot = 0; ot < 2; ++ot) {
#pragma unroll
        for (int kh = 0; kh < 2; ++kh) {
          const bf16x8 wfq =
              w_frag(wq + (size_t)(16 * ot + q16) * CH + c0 + 32 * kh + quad * 8);
          accQ[ot] = __builtin_amdgcn_mfma_f32_16x16x32_bf16(afQ[kh], wfq, accQ[ot], 0, 0, 0);
          const bf16x8 wfk =
              w_frag(wk + (size_t)(16 * ot + q16) * CH + c0 + 32 * kh + quad * 8);
          accK[ot] = __builtin_amdgcn_mfma_f32_16x16x32_bf16(afK[kh], wfk, accK[ot], 0, 0, 0);
        }
      }
    }
    const float bq0 = bq[q16], bq1 = bq[16 + q16];
    const float bk0 = bk[q16], bk1 = bk[16 + q16];
#pragma unroll
    for (int r = 0; r < 4; ++r) {
      const size_t row = (size_t)b * HWPIX + n0 + 16 * w + quad * 4 + r;
      qT[row * CQK_ + q16]      = (__bf16)(accQ[0][r] + bq0);
      qT[row * CQK_ + 16 + q16] = (__bf16)(accQ[1][r] + bq1);
      kT[row * CQK_ + q16]      = (__bf16)(accK[0][r] + bk0);
      kT[row * CQK_ + 16 + q16] = (__bf16)(accK[1][r] + bk1);
    }
  } else {
    const int cbase = (mode - 1) * 128;
    const float* f3b = f3 + (size_t)b * CH * HWPIX + n0;
    f32x4 acc[2][4];
#pragma unroll
    for (int ct = 0; ct < 2; ++ct)
#pragma unroll
      for (int nt = 0; nt < 4; ++nt) acc[ct][nt] = (f32x4){0.f, 0.f, 0.f, 0.f};

    float4 rV[4];
    STAGE_LOAD(f3b, 0, rV);
    for (int c0 = 0; c0 < CH; c0 += 64) {
      __syncthreads();
      STAGE_WRITE(rV, f_s[0]);
      __syncthreads();
      if (c0 < CH - 64) STAGE_LOAD(f3b, c0 + 64, rV);
      bf16x8 af[2][2];  // [ct][kh] : W rows (c)
#pragma unroll
      for (int ct = 0; ct < 2; ++ct)
#pragma unroll
        for (int kh = 0; kh < 2; ++kh)
          af[ct][kh] = w_frag(wv + (size_t)(cbase + 64 * ct + 16 * w + q16) * CH
                              + c0 + 32 * kh + quad * 8);
#pragma unroll
      for (int nt = 0; nt < 4; ++nt) {
#pragma unroll
        for (int kh = 0; kh < 2; ++kh) {
          const bf16x8 bfr = ld_frag(&f_s[0][(16 * nt + q16) * FS_STR + 32 * kh + quad * 8]);
#pragma unroll
          for (int ct = 0; ct < 2; ++ct)
            acc[ct][nt] = __builtin_amdgcn_mfma_f32_16x16x32_bf16(
                af[ct][kh], bfr, acc[ct][nt], 0, 0, 0);
        }
      }
    }
#pragma unroll
    for (int ct = 0; ct < 2; ++ct) {
      const float4 bi = *(const float4*)&bv[cbase + 64 * ct + 16 * w + quad * 4];
#pragma unroll
      for (int nt = 0; nt < 4; ++nt) {
#pragma unroll
        for (int r = 0; r < 4; ++r) {
          const int c = cbase + 64 * ct + 16 * w + quad * 4 + r;
          vv[((size_t)b * CH + c) * HWPIX + n0 + 16 * nt + q16] =
              (__bf16)(acc[ct][nt][r] + ((const float*)&bi)[r]);
        }
      }
    }
  }
#undef STAGE_LOAD
#undef STAGE_WRITE
}

// ---- Pipelined flash attention (R1/R4 structure, 163 us total).
// Split into two half-grid dispatches (qoff = 0, 32) so each dispatch
// (~82 us) drops below proj_all (~150 us) and proj surfaces in the rocprof
// top-5 with counters. Bit-identical math; blocks independent per (b,q-tile);
// R1 proved occupancy-insensitivity (21.8% vs 44.2% -> identical 164 us).
// grid 256: b = bx&7 (XCD-pinned), q-tile = (bx>>3) + qoff.
__global__ __launch_bounds__(512, 4) void attn_kernel(
    const __bf16* __restrict__ qT, const __bf16* __restrict__ kT,
    const __bf16* __restrict__ vv, float* __restrict__ out, int qoff)
{
  __shared__ __align__(16) __bf16 p_s[2][64 * 64];  // [q][m], stride 64 bf16 = 128 B
  __shared__ float L_s[2][64];

  const int t    = threadIdx.x;
  const int w    = __builtin_amdgcn_readfirstlane(t >> 6);
  const int lane = t & 63;
  const int q16  = lane & 15;
  const int quad = lane >> 4;
  const int qb   = w & 3;   // score q-block (16 rows)
  const int hb   = w >> 2;  // score m-half (32 of 64 keys)
  const int swz  = (q16 & 7) << 4;

  const int b  = blockIdx.x & 7;
  const int q0 = ((blockIdx.x >> 3) + qoff) * 64;

  const __bf16* kTb = kT + (size_t)b * HWPIX * CQK_;
  // lane offset within a 64-key K tile: key = 32*hb + 16*mt + q16, ck = quad*8..+8
  const size_t koff = (size_t)(32 * hb + q16) * CQK_ + quad * 8;

  // running V pointers (advance 64 keys = 128 B per iter); ch = 32w + 16ct + q16
  const __bf16* vp[2];
#pragma unroll
  for (int ct = 0; ct < 2; ++ct)
    vp[ct] = vv + ((size_t)b * CH + 32 * w + 16 * ct + q16) * HWPIX + quad * 8;

  // Q fragment: q row = q0 + 16*qb + q16 (B-operand in swapped scores)
  const bf16x8 qfrag =
      *(const bf16x8*)(qT + ((size_t)b * HWPIX + q0 + 16 * qb + q16) * CQK_ + quad * 8);

  f32x4 oacc[2][4];
#pragma unroll
  for (int i = 0; i < 2; ++i)
#pragma unroll
    for (int j = 0; j < 4; ++j)
      oacc[i][j] = (f32x4){0.f, 0.f, 0.f, 0.f};
  float Lp = 0.f;  // lane-local partial row-sum (q row 16qb+q16, m-half hb)

  // ---- prologue: scores tile 0 -> p_s[0]; kf <- tile 1
  bf16x8 kf[2];
#pragma unroll
  for (int mt = 0; mt < 2; ++mt)
    kf[mt] = *(const bf16x8*)(kTb + koff + mt * 512);
  {
    f32x4 Sv[2];
#pragma unroll
    for (int mt = 0; mt < 2; ++mt)
      Sv[mt] = __builtin_amdgcn_mfma_f32_16x16x32_bf16(
          kf[mt], qfrag, (f32x4){0.f, 0.f, 0.f, 0.f}, 0, 0, 0);
    const __bf16* kb1 = kTb + 64 * CQK_;
#pragma unroll
    for (int mt = 0; mt < 2; ++mt)
      kf[mt] = *(const bf16x8*)(kb1 + koff + mt * 512);
    char* pw = (char*)p_s[0] + (16 * qb + q16) * 128;
#pragma unroll
    for (int mt = 0; mt < 2; ++mt) {
      bf16x4 pk;
#pragma unroll
      for (int r = 0; r < 4; ++r) {
        const float e = __expf(Sv[mt][r]);  // key = 32hb + 16mt + 4quad + r
        Lp += e;
        pk[r] = (__bf16)e;
      }
      *(bf16x4*)(pw + ((64 * hb + 32 * mt + 8 * quad) ^ swz)) = pk;
    }
  }
  __syncthreads();

  // ---- main loop: iter i does AV for tile i, scores+exp for tile i+1
  for (int i = 0; i < 64; ++i) {
    // V fragments for tile i (issued first; consumed after score/exp phase)
    bf16x8 vf[2][2];
#pragma unroll
    for (int ct = 0; ct < 2; ++ct)
#pragma unroll
      for (int mh = 0; mh < 2; ++mh)
        vf[ct][mh] = *(const bf16x8*)(vp[ct] + mh * 32);

    // P fragments for tile i (swizzled reads; all 64 q rows)
    const char* pb = (const char*)p_s[i & 1];
    bf16x8 pf[4][2];
#pragma unroll
    for (int nt = 0; nt < 4; ++nt)
#pragma unroll
      for (int mh = 0; mh < 2; ++mh)
        pf[nt][mh] = *(const bf16x8*)(pb + (16 * nt + q16) * 128
                                      + ((64 * mh + 16 * quad) ^ swz));

    if (i < 63) {
      // scores for tile i+1 (kf prefetched last iter), swapped operands
      f32x4 Sv[2];
#pragma unroll
      for (int mt = 0; mt < 2; ++mt)
        Sv[mt] = __builtin_amdgcn_mfma_f32_16x16x32_bf16(
            kf[mt], qfrag, (f32x4){0.f, 0.f, 0.f, 0.f}, 0, 0, 0);
      // prefetch kf for tile i+2
      const __bf16* kb2 = kTb + (size_t)((i + 2) & 63) * (64 * CQK_);
#pragma unroll
      for (int mt = 0; mt < 2; ++mt)
        kf[mt] = *(const bf16x8*)(kb2 + koff + mt * 512);
      // exp + packed b64 write of P[i+1] into the other buffer
      char* pw = (char*)p_s[(i + 1) & 1] + (16 * qb + q16) * 128;
#pragma unroll
      for (int mt = 0; mt < 2; ++mt) {
        bf16x4 pk;
#pragma unroll
        for (int r = 0; r < 4; ++r) {
          const float e = __expf(Sv[mt][r]);
          Lp += e;
          pk[r] = (__bf16)e;
        }
        *(bf16x4*)(pw + ((64 * hb + 32 * mt + 8 * quad) ^ swz)) = pk;
      }
    }

    // AV for tile i: O[ch = 32w+16ct+...][q = 16nt+...] += V * P
#pragma unroll
    for (int ct = 0; ct < 2; ++ct)
#pragma unroll
      for (int nt = 0; nt < 4; ++nt)
#pragma unroll
        for (int mh = 0; mh < 2; ++mh)
          oacc[ct][nt] = __builtin_amdgcn_mfma_f32_16x16x32_bf16(
              vf[ct][mh], pf[nt][mh], oacc[ct][nt], 0, 0, 0);

#pragma unroll
    for (int ct = 0; ct < 2; ++ct) vp[ct] += 64;
    __syncthreads();
  }

  // ---- finalize L: lane-local partial -> sum over the 4 quads (same q16)
  Lp += __shfl_xor(Lp, 16);
  Lp += __shfl_xor(Lp, 32);
  if (quad == 0) L_s[hb][16 * qb + q16] = Lp;
  __syncthreads();

  float rinv[4];
#pragma unroll
  for (int nt = 0; nt < 4; ++nt)
    rinv[nt] = 1.0f / (L_s[0][16 * nt + q16] + L_s[1][16 * nt + q16]);

  float* ob = out + ((size_t)b * CH + 32 * w) * HWPIX + q0;
#pragma unroll
  for (int ct = 0; ct < 2; ++ct)
#pragma unroll
    for (int r = 0; r < 4; ++r)
#pragma unroll
      for (int nt = 0; nt < 4; ++nt)
        ob[(size_t)(16 * ct + quad * 4 + r) * HWPIX + 16 * nt + q16] =
            oacc[ct][nt][r] * rinv[nt];
}

extern "C" void kernel_launch(void* const* d_in, const int* in_sizes, int n_in,
                              void* d_out, int out_size, void* d_ws, size_t ws_size,
                              hipStream_t stream)
{
  const float* f1 = (const float*)d_in[0];
  const float* f2 = (const float*)d_in[1];
  const float* f3 = (const float*)d_in[2];
  const float* wq = (const float*)d_in[3];
  const float* bq = (const float*)d_in[4];
  const float* wk = (const float*)d_in[5];
  const float* bk = (const float*)d_in[6];
  const float* wv = (const float*)d_in[7];
  const float* bv = (const float*)d_in[8];
  float* outp = (float*)d_out;

  // workspace: qT [8][4096][32] | kT [8][4096][32] | v [8][256][4096]  (bf16, 20 MB)
  __bf16* qTw = (__bf16*)d_ws;
  __bf16* kTw = qTw + (size_t)BATCH * HWPIX * CQK_;
  __bf16* vw  = kTw + (size_t)BATCH * HWPIX * CQK_;

  proj_all<<<dim3(64, 3, 8), 256, 0, stream>>>(f1, f2, f3, wq, bq, wk, bk, wv, bv,
                                               qTw, kTw, vw);
  // attn split into two half-grid dispatches purely so proj_all surfaces in
  // the rocprof top-5 (each half ~82 us < proj ~150 us). Bit-identical math.
  attn_kernel<<<dim3(256), 512, 0, stream>>>(qTw, kTw, vw, outp, 0);
  attn_kernel<<<dim3(256), 512, 0, stream>>>(qTw, kTw, vw, outp, 32);
}

// Round 7
// 305.424 us; speedup vs baseline: 1.1149x; 1.1149x over previous
//
#include <hip/hip_runtime.h>
#include <math.h>

#define BATCH 8
#define CH    256
#define HWPIX 4096
#define CQK_  32

typedef __bf16 bf16x8 __attribute__((ext_vector_type(8)));
typedef __bf16 bf16x4 __attribute__((ext_vector_type(4)));
typedef __bf16 bf16x2 __attribute__((ext_vector_type(2)));
typedef float  f32x4  __attribute__((ext_vector_type(4)));

#define FS_STR 68   // LDS transpose-tile row stride in bf16 (136 B: 8B-aligned)

// load a bf16x8 fragment from LDS as two 8B halves (rows only 8B-aligned)
static __device__ inline bf16x8 ld_frag(const __bf16* p) {
  bf16x4 lo = *(const bf16x4*)p;
  bf16x4 hi = *(const bf16x4*)(p + 4);
  return __builtin_shufflevector(lo, hi, 0, 1, 2, 3, 4, 5, 6, 7);
}

// load 8 consecutive fp32 from a W row, convert to bf16x8 fragment
static __device__ inline bf16x8 w_frag(const float* p) {
  const float4 a = *(const float4*)p;
  const float4 b = *(const float4*)(p + 4);
  bf16x8 r;
  r[0] = (__bf16)a.x; r[1] = (__bf16)a.y; r[2] = (__bf16)a.z; r[3] = (__bf16)a.w;
  r[4] = (__bf16)b.x; r[5] = (__bf16)b.y; r[6] = (__bf16)b.z; r[7] = (__bf16)b.w;
  return r;
}

// ---- Fused projections, single-read-per-input version.
// R6 ledger: proj is HBM-bound (~530 MB incl. a DUPLICATE f3 read by the two
// V c-half modes). This version reads each input exactly once (~403 MB).
// grid (64 n-tiles, 2 modes, 8 b), block 512 = 8 waves.
// mode 0 (QK): waves 0-3 stage f1 -> f_s[0], compute Q; waves 4-7 stage
//   f2 -> f_s[1], compute K. Per wave: 16 q-rows, acc[2] (32 out-ch).
// mode 1 (V): all 512 threads stage the 64x64 f3 tile once; wave w computes
//   out-channels [32w, +32) for all 64 pixels (acc[2][4]).
__global__ __launch_bounds__(512, 4) void proj_all(
    const float* __restrict__ f1, const float* __restrict__ f2,
    const float* __restrict__ f3,
    const float* __restrict__ wq, const float* __restrict__ bq,
    const float* __restrict__ wk, const float* __restrict__ bk,
    const float* __restrict__ wv, const float* __restrict__ bv,
    __bf16* __restrict__ qT, __bf16* __restrict__ kT, __bf16* __restrict__ vv)
{
  __shared__ __align__(16) __bf16 f_s[2][64 * FS_STR];  // [n][cin] transposed tiles
  const int t    = threadIdx.x;
  const int w    = __builtin_amdgcn_readfirstlane(t >> 6);
  const int lane = t & 63;
  const int q16  = lane & 15;
  const int quad = lane >> 4;
  const int b    = blockIdx.z;
  const int n0   = blockIdx.x * 64;
  const int mode = blockIdx.y;

  if (mode == 0) {
    // ---- QK: two independent 256-thread staging halves, 8 compute waves.
    const int half = t >> 8;           // 0: f1/Q lane, 1: f2/K lane
    const int th   = t & 255;
    const int sn   = (th & 15) * 4;    // pixel offset within the 64-tile
    const int scp  = (th >> 4) * 2;    // channel-pair base (0..30)
    const int qr   = w & 3;            // wave's 16-row group
    const int isK  = w >> 2;           // 0 = Q group, 1 = K group

    const float* fsrc = (half ? f2 : f1) + (size_t)b * CH * HWPIX + n0;
    __bf16* fdst = f_s[half];

    f32x4 acc[2];
#pragma unroll
    for (int i = 0; i < 2; ++i) acc[i] = (f32x4){0.f, 0.f, 0.f, 0.f};

    float4 rg[4];
#pragma unroll
    for (int rr = 0; rr < 2; ++rr) {
      const int c = rr * 32 + scp;
      rg[2 * rr + 0] = *(const float4*)&fsrc[(size_t)(c)     * HWPIX + sn];
      rg[2 * rr + 1] = *(const float4*)&fsrc[(size_t)(c + 1) * HWPIX + sn];
    }

    const float* wmat = isK ? wk : wq;
    for (int c0 = 0; c0 < CH; c0 += 64) {
      __syncthreads();  // previous iter's readers done; LDS reusable
#pragma unroll
      for (int rr = 0; rr < 2; ++rr) {
        const int c = rr * 32 + scp;
#pragma unroll
        for (int i = 0; i < 4; ++i) {
          bf16x2 pk;
          pk[0] = (__bf16)((const float*)&rg[2 * rr + 0])[i];
          pk[1] = (__bf16)((const float*)&rg[2 * rr + 1])[i];
          *(bf16x2*)&fdst[(sn + i) * FS_STR + c] = pk;
        }
      }
      __syncthreads();
      if (c0 < CH - 64) {  // prefetch next c-tile; latency hides under compute
#pragma unroll
        for (int rr = 0; rr < 2; ++rr) {
          const int c = rr * 32 + scp;
          rg[2 * rr + 0] = *(const float4*)&fsrc[(size_t)(c0 + 64 + c)     * HWPIX + sn];
          rg[2 * rr + 1] = *(const float4*)&fsrc[(size_t)(c0 + 64 + c + 1) * HWPIX + sn];
        }
      }
      bf16x8 af[2];
#pragma unroll
      for (int kh = 0; kh < 2; ++kh)
        af[kh] = ld_frag(&f_s[isK][(16 * qr + q16) * FS_STR + 32 * kh + quad * 8]);
#pragma unroll
      for (int ot = 0; ot < 2; ++ot) {
#pragma unroll
        for (int kh = 0; kh < 2; ++kh) {
          const bf16x8 wf =
              w_frag(wmat + (size_t)(16 * ot + q16) * CH + c0 + 32 * kh + quad * 8);
          acc[ot] = __builtin_amdgcn_mfma_f32_16x16x32_bf16(af[kh], wf, acc[ot], 0, 0, 0);
        }
      }
    }
    const float* bias = isK ? bk : bq;
    __bf16* outT = isK ? kT : qT;
    const float b0 = bias[q16], b1 = bias[16 + q16];
#pragma unroll
    for (int r = 0; r < 4; ++r) {
      const size_t row = (size_t)b * HWPIX + n0 + 16 * qr + quad * 4 + r;
      outT[row * CQK_ + q16]      = (__bf16)(acc[0][r] + b0);
      outT[row * CQK_ + 16 + q16] = (__bf16)(acc[1][r] + b1);
    }
  } else {
    // ---- V: stage f3 tile ONCE, compute all 256 out-channels (32 per wave).
    const int sn = (t & 15) * 4;       // pixel offset
    const int c2 = (t >> 4) * 2;       // channel pair (0..62), 32 pairs
    const float* f3b = f3 + (size_t)b * CH * HWPIX + n0;

    f32x4 acc[2][4];
#pragma unroll
    for (int ct = 0; ct < 2; ++ct)
#pragma unroll
      for (int nt = 0; nt < 4; ++nt) acc[ct][nt] = (f32x4){0.f, 0.f, 0.f, 0.f};

    float4 r0 = *(const float4*)&f3b[(size_t)(c2)     * HWPIX + sn];
    float4 r1 = *(const float4*)&f3b[(size_t)(c2 + 1) * HWPIX + sn];

    for (int c0 = 0; c0 < CH; c0 += 64) {
      __syncthreads();
#pragma unroll
      for (int i = 0; i < 4; ++i) {
        bf16x2 pk;
        pk[0] = (__bf16)((const float*)&r0)[i];
        pk[1] = (__bf16)((const float*)&r1)[i];
        *(bf16x2*)&f_s[0][(sn + i) * FS_STR + c2] = pk;
      }
      __syncthreads();
      if (c0 < CH - 64) {
        r0 = *(const float4*)&f3b[(size_t)(c0 + 64 + c2)     * HWPIX + sn];
        r1 = *(const float4*)&f3b[(size_t)(c0 + 64 + c2 + 1) * HWPIX + sn];
      }
      bf16x8 af[2][2];  // [ct][kh] : W rows (out-ch = 32w + 16ct + q16)
#pragma unroll
      for (int ct = 0; ct < 2; ++ct)
#pragma unroll
        for (int kh = 0; kh < 2; ++kh)
          af[ct][kh] = w_frag(wv + (size_t)(32 * w + 16 * ct + q16) * CH
                              + c0 + 32 * kh + quad * 8);
#pragma unroll
      for (int nt = 0; nt < 4; ++nt) {
#pragma unroll
        for (int kh = 0; kh < 2; ++kh) {
          const bf16x8 bfr = ld_frag(&f_s[0][(16 * nt + q16) * FS_STR + 32 * kh + quad * 8]);
#pragma unroll
          for (int ct = 0; ct < 2; ++ct)
            acc[ct][nt] = __builtin_amdgcn_mfma_f32_16x16x32_bf16(
                af[ct][kh], bfr, acc[ct][nt], 0, 0, 0);
        }
      }
    }
#pragma unroll
    for (int ct = 0; ct < 2; ++ct) {
      const float4 bi = *(const float4*)&bv[32 * w + 16 * ct + quad * 4];
#pragma unroll
      for (int nt = 0; nt < 4; ++nt) {
#pragma unroll
        for (int r = 0; r < 4; ++r) {
          const int c = 32 * w + 16 * ct + quad * 4 + r;
          vv[((size_t)b * CH + c) * HWPIX + n0 + 16 * nt + q16] =
              (__bf16)(acc[ct][nt][r] + ((const float*)&bi)[r]);
        }
      }
    }
  }
}

// ---- Pipelined flash attention (R1/R4 structure, verified 163 us; fused
// single dispatch restored — the R6 split cost +31 us and has served its
// measurement purpose). 8 waves/block (512 thr). grid 512: b = bx&7
// (XCD-pinned), q-tile = bx>>3.
// Scores: wave w owns q rows [16*(w&3), +16) x m half (w>>2)*32, SWAPPED mfma(K,Q).
// AV: wave w owns output channels [32w, +32).
// P tile: [64 q][64 m] bf16, 128 B rows, byte ^= ((q16&7)<<4) XOR swizzle.
__global__ __launch_bounds__(512, 4) void attn_kernel(
    const __bf16* __restrict__ qT, const __bf16* __restrict__ kT,
    const __bf16* __restrict__ vv, float* __restrict__ out)
{
  __shared__ __align__(16) __bf16 p_s[2][64 * 64];  // [q][m], stride 64 bf16 = 128 B
  __shared__ float L_s[2][64];

  const int t    = threadIdx.x;
  const int w    = __builtin_amdgcn_readfirstlane(t >> 6);
  const int lane = t & 63;
  const int q16  = lane & 15;
  const int quad = lane >> 4;
  const int qb   = w & 3;   // score q-block (16 rows)
  const int hb   = w >> 2;  // score m-half (32 of 64 keys)
  const int swz  = (q16 & 7) << 4;

  const int b  = blockIdx.x & 7;
  const int q0 = (blockIdx.x >> 3) * 64;

  const __bf16* kTb = kT + (size_t)b * HWPIX * CQK_;
  // lane offset within a 64-key K tile: key = 32*hb + 16*mt + q16, ck = quad*8..+8
  const size_t koff = (size_t)(32 * hb + q16) * CQK_ + quad * 8;

  // running V pointers (advance 64 keys = 128 B per iter); ch = 32w + 16ct + q16
  const __bf16* vp[2];
#pragma unroll
  for (int ct = 0; ct < 2; ++ct)
    vp[ct] = vv + ((size_t)b * CH + 32 * w + 16 * ct + q16) * HWPIX + quad * 8;

  // Q fragment: q row = q0 + 16*qb + q16 (B-operand in swapped scores)
  const bf16x8 qfrag =
      *(const bf16x8*)(qT + ((size_t)b * HWPIX + q0 + 16 * qb + q16) * CQK_ + quad * 8);

  f32x4 oacc[2][4];
#pragma unroll
  for (int i = 0; i < 2; ++i)
#pragma unroll
    for (int j = 0; j < 4; ++j)
      oacc[i][j] = (f32x4){0.f, 0.f, 0.f, 0.f};
  float Lp = 0.f;  // lane-local partial row-sum (q row 16qb+q16, m-half hb)

  // ---- prologue: scores tile 0 -> p_s[0]; kf <- tile 1
  bf16x8 kf[2];
#pragma unroll
  for (int mt = 0; mt < 2; ++mt)
    kf[mt] = *(const bf16x8*)(kTb + koff + mt * 512);
  {
    f32x4 Sv[2];
#pragma unroll
    for (int mt = 0; mt < 2; ++mt)
      Sv[mt] = __builtin_amdgcn_mfma_f32_16x16x32_bf16(
          kf[mt], qfrag, (f32x4){0.f, 0.f, 0.f, 0.f}, 0, 0, 0);
    const __bf16* kb1 = kTb + 64 * CQK_;
#pragma unroll
    for (int mt = 0; mt < 2; ++mt)
      kf[mt] = *(const bf16x8*)(kb1 + koff + mt * 512);
    char* pw = (char*)p_s[0] + (16 * qb + q16) * 128;
#pragma unroll
    for (int mt = 0; mt < 2; ++mt) {
      bf16x4 pk;
#pragma unroll
      for (int r = 0; r < 4; ++r) {
        const float e = __expf(Sv[mt][r]);  // key = 32hb + 16mt + 4quad + r
        Lp += e;
        pk[r] = (__bf16)e;
      }
      *(bf16x4*)(pw + ((64 * hb + 32 * mt + 8 * quad) ^ swz)) = pk;
    }
  }
  __syncthreads();

  // ---- main loop: iter i does AV for tile i, scores+exp for tile i+1
  for (int i = 0; i < 64; ++i) {
    // V fragments for tile i (issued first; consumed after score/exp phase)
    bf16x8 vf[2][2];
#pragma unroll
    for (int ct = 0; ct < 2; ++ct)
#pragma unroll
      for (int mh = 0; mh < 2; ++mh)
        vf[ct][mh] = *(const bf16x8*)(vp[ct] + mh * 32);

    // P fragments for tile i (swizzled reads; all 64 q rows)
    const char* pb = (const char*)p_s[i & 1];
    bf16x8 pf[4][2];
#pragma unroll
    for (int nt = 0; nt < 4; ++nt)
#pragma unroll
      for (int mh = 0; mh < 2; ++mh)
        pf[nt][mh] = *(const bf16x8*)(pb + (16 * nt + q16) * 128
                                      + ((64 * mh + 16 * quad) ^ swz));

    if (i < 63) {
      // scores for tile i+1 (kf prefetched last iter), swapped operands
      f32x4 Sv[2];
#pragma unroll
      for (int mt = 0; mt < 2; ++mt)
        Sv[mt] = __builtin_amdgcn_mfma_f32_16x16x32_bf16(
            kf[mt], qfrag, (f32x4){0.f, 0.f, 0.f, 0.f}, 0, 0, 0);
      // prefetch kf for tile i+2
      const __bf16* kb2 = kTb + (size_t)((i + 2) & 63) * (64 * CQK_);
#pragma unroll
      for (int mt = 0; mt < 2; ++mt)
        kf[mt] = *(const bf16x8*)(kb2 + koff + mt * 512);
      // exp + packed b64 write of P[i+1] into the other buffer
      char* pw = (char*)p_s[(i + 1) & 1] + (16 * qb + q16) * 128;
#pragma unroll
      for (int mt = 0; mt < 2; ++mt) {
        bf16x4 pk;
#pragma unroll
        for (int r = 0; r < 4; ++r) {
          const float e = __expf(Sv[mt][r]);
          Lp += e;
          pk[r] = (__bf16)e;
        }
        *(bf16x4*)(pw + ((64 * hb + 32 * mt + 8 * quad) ^ swz)) = pk;
      }
    }

    // AV for tile i: O[ch = 32w+16ct+...][q = 16nt+...] += V * P
#pragma unroll
    for (int ct = 0; ct < 2; ++ct)
#pragma unroll
      for (int nt = 0; nt < 4; ++nt)
#pragma unroll
        for (int mh = 0; mh < 2; ++mh)
          oacc[ct][nt] = __builtin_amdgcn_mfma_f32_16x16x32_bf16(
              vf[ct][mh], pf[nt][mh], oacc[ct][nt], 0, 0, 0);

#pragma unroll
    for (int ct = 0; ct < 2; ++ct) vp[ct] += 64;
    __syncthreads();
  }

  // ---- finalize L: lane-local partial -> sum over the 4 quads (same q16)
  Lp += __shfl_xor(Lp, 16);
  Lp += __shfl_xor(Lp, 32);
  if (quad == 0) L_s[hb][16 * qb + q16] = Lp;
  __syncthreads();

  float rinv[4];
#pragma unroll
  for (int nt = 0; nt < 4; ++nt)
    rinv[nt] = 1.0f / (L_s[0][16 * nt + q16] + L_s[1][16 * nt + q16]);

  float* ob = out + ((size_t)b * CH + 32 * w) * HWPIX + q0;
#pragma unroll
  for (int ct = 0; ct < 2; ++ct)
#pragma unroll
    for (int r = 0; r < 4; ++r)
#pragma unroll
      for (int nt = 0; nt < 4; ++nt)
        ob[(size_t)(16 * ct + quad * 4 + r) * HWPIX + 16 * nt + q16] =
            oacc[ct][nt][r] * rinv[nt];
}

extern "C" void kernel_launch(void* const* d_in, const int* in_sizes, int n_in,
                              void* d_out, int out_size, void* d_ws, size_t ws_size,
                              hipStream_t stream)
{
  const float* f1 = (const float*)d_in[0];
  const float* f2 = (const float*)d_in[1];
  const float* f3 = (const float*)d_in[2];
  const float* wq = (const float*)d_in[3];
  const float* bq = (const float*)d_in[4];
  const float* wk = (const float*)d_in[5];
  const float* bk = (const float*)d_in[6];
  const float* wv = (const float*)d_in[7];
  const float* bv = (const float*)d_in[8];
  float* outp = (float*)d_out;

  // workspace: qT [8][4096][32] | kT [8][4096][32] | v [8][256][4096]  (bf16, 20 MB)
  __bf16* qTw = (__bf16*)d_ws;
  __bf16* kTw = qTw + (size_t)BATCH * HWPIX * CQK_;
  __bf16* vw  = kTw + (size_t)BATCH * HWPIX * CQK_;

  proj_all<<<dim3(64, 2, 8), 512, 0, stream>>>(f1, f2, f3, wq, bq, wk, bk, wv, bv,
                                               qTw, kTw, vw);
  attn_kernel<<<dim3(512), 512, 0, stream>>>(qTw, kTw, vw, outp);
}

// Round 10
// 295.589 us; speedup vs baseline: 1.1520x; 1.0333x over previous
//
#include <hip/hip_runtime.h>
#include <math.h>

#define BATCH 8
#define CH    256
#define HWPIX 4096
#define CQK_  32

typedef __bf16 bf16x8 __attribute__((ext_vector_type(8)));
typedef __bf16 bf16x4 __attribute__((ext_vector_type(4)));
typedef __bf16 bf16x2 __attribute__((ext_vector_type(2)));
typedef float  f32x4  __attribute__((ext_vector_type(4)));

#define FS_STR 68   // LDS transpose-tile row stride in bf16 (136 B: 8B-aligned)

// load a bf16x8 fragment from LDS as two 8B halves (rows only 8B-aligned)
static __device__ inline bf16x8 ld_frag(const __bf16* p) {
  bf16x4 lo = *(const bf16x4*)p;
  bf16x4 hi = *(const bf16x4*)(p + 4);
  return __builtin_shufflevector(lo, hi, 0, 1, 2, 3, 4, 5, 6, 7);
}

// load 8 consecutive fp32 from a W row, convert to bf16x8 fragment
static __device__ inline bf16x8 w_frag(const float* p) {
  const float4 a = *(const float4*)p;
  const float4 b = *(const float4*)(p + 4);
  bf16x8 r;
  r[0] = (__bf16)a.x; r[1] = (__bf16)a.y; r[2] = (__bf16)a.z; r[3] = (__bf16)a.w;
  r[4] = (__bf16)b.x; r[5] = (__bf16)b.y; r[6] = (__bf16)b.z; r[7] = (__bf16)b.w;
  return r;
}

// ---- Fused projections, 128-pixel tiles for 512 B DRAM chunks.
// R7 ledger: proj ~85 us vs 64 us HBM floor; 64-px tiles cap reads at 256 B
// contiguous (~85% DRAM eff). 128-px tiles double the chunk to 512 B.
// grid (32 n-tiles, 2 modes, 8 b), block 512 = 8 waves.
// mode 0 (QK): threads<256 stage f1 -> f_s[0], threads>=256 stage f2 -> f_s[1];
//   waves 0-3 compute Q (32 px-rows each), waves 4-7 compute K.
// mode 1 (V): all 512 threads stage the 128x64 f3 c-tile once; wave w computes
//   out-channels [32w,+32) for all 128 pixels (acc[2][8]).
__global__ __launch_bounds__(512, 4) void proj_all(
    const float* __restrict__ f1, const float* __restrict__ f2,
    const float* __restrict__ f3,
    const float* __restrict__ wq, const float* __restrict__ bq,
    const float* __restrict__ wk, const float* __restrict__ bk,
    const float* __restrict__ wv, const float* __restrict__ bv,
    __bf16* __restrict__ qT, __bf16* __restrict__ kT, __bf16* __restrict__ vv)
{
  __shared__ __align__(16) __bf16 f_s[2][128 * FS_STR];  // [px][cin] transposed
  const int t    = threadIdx.x;
  const int w    = __builtin_amdgcn_readfirstlane(t >> 6);
  const int lane = t & 63;
  const int q16  = lane & 15;
  const int quad = lane >> 4;
  const int b    = blockIdx.z;
  const int n0   = blockIdx.x * 128;
  const int mode = blockIdx.y;

  if (mode == 0) {
    const int half = t >> 8;          // 0: f1/Q staging, 1: f2/K staging
    const int th   = t & 255;
    const int px   = (th & 31) * 4;   // pixel 0..124 -> 32 thr x float4 = 512 B/ch
    const int g2   = (th >> 5) * 2;   // channel-pair base 0..14
    const int isK  = w >> 2;          // waves 0-3: Q, 4-7: K
    const int qr   = w & 3;           // 32-pixel row group

    const float* fsrc = (half ? f2 : f1) + (size_t)b * CH * HWPIX + n0;
    __bf16* fdst = f_s[half];
    const float* wmat = isK ? wk : wq;

    f32x4 acc[2][2];  // [ot][rg]
#pragma unroll
    for (int i = 0; i < 2; ++i)
#pragma unroll
      for (int j = 0; j < 2; ++j) acc[i][j] = (f32x4){0.f, 0.f, 0.f, 0.f};

    float4 rg_[8];
#define PLOAD(c0)                                                               \
    _Pragma("unroll") for (int cc = 0; cc < 4; ++cc) {                          \
      const int c = (c0) + 16 * cc + g2;                                        \
      rg_[2 * cc]     = *(const float4*)&fsrc[(size_t)c * HWPIX + px];          \
      rg_[2 * cc + 1] = *(const float4*)&fsrc[(size_t)(c + 1) * HWPIX + px];    \
    }
    PLOAD(0);
    for (int c0 = 0; c0 < CH; c0 += 64) {
      __syncthreads();  // previous iter's readers done; LDS reusable
#pragma unroll
      for (int cc = 0; cc < 4; ++cc) {
        const int c = 16 * cc + g2;
#pragma unroll
        for (int i = 0; i < 4; ++i) {
          bf16x2 pk;
          pk[0] = (__bf16)((const float*)&rg_[2 * cc])[i];
          pk[1] = (__bf16)((const float*)&rg_[2 * cc + 1])[i];
          *(bf16x2*)&fdst[(px + i) * FS_STR + c] = pk;
        }
      }
      __syncthreads();
      if (c0 < CH - 64) PLOAD(c0 + 64);  // prefetch; hides under compute
      bf16x8 af[2][2];  // [rg][kh]
#pragma unroll
      for (int rg = 0; rg < 2; ++rg)
#pragma unroll
        for (int kh = 0; kh < 2; ++kh)
          af[rg][kh] = ld_frag(&f_s[isK][(32 * qr + 16 * rg + q16) * FS_STR
                                         + 32 * kh + quad * 8]);
#pragma unroll
      for (int ot = 0; ot < 2; ++ot)
#pragma unroll
        for (int kh = 0; kh < 2; ++kh) {
          const bf16x8 wf =
              w_frag(wmat + (size_t)(16 * ot + q16) * CH + c0 + 32 * kh + quad * 8);
#pragma unroll
          for (int rg = 0; rg < 2; ++rg)
            acc[ot][rg] = __builtin_amdgcn_mfma_f32_16x16x32_bf16(
                af[rg][kh], wf, acc[ot][rg], 0, 0, 0);
        }
    }
    const float* bias = isK ? bk : bq;
    __bf16* outT = isK ? kT : qT;
    const float b0 = bias[q16], b1 = bias[16 + q16];
#pragma unroll
    for (int rg = 0; rg < 2; ++rg)
#pragma unroll
      for (int r = 0; r < 4; ++r) {
        const size_t row = (size_t)b * HWPIX + n0 + 32 * qr + 16 * rg + quad * 4 + r;
        outT[row * CQK_ + q16]      = (__bf16)(acc[0][rg][r] + b0);
        outT[row * CQK_ + 16 + q16] = (__bf16)(acc[1][rg][r] + b1);
      }
#undef PLOAD
  } else {
    // ---- V: stage 128x64 f3 c-tile once; 256 out-ch, 32 per wave.
    const int px = (t & 31) * 4;
    const int g2 = (t >> 5) * 2;   // channel-pair base 0..30
    const float* f3b = f3 + (size_t)b * CH * HWPIX + n0;

    f32x4 acc[2][8];  // [ct][nt]
#pragma unroll
    for (int ct = 0; ct < 2; ++ct)
#pragma unroll
      for (int nt = 0; nt < 8; ++nt) acc[ct][nt] = (f32x4){0.f, 0.f, 0.f, 0.f};

    float4 r_[4];
#define VLOAD(c0)                                                               \
    _Pragma("unroll") for (int cc = 0; cc < 2; ++cc) {                          \
      const int c = (c0) + 32 * cc + g2;                                        \
      r_[2 * cc]     = *(const float4*)&f3b[(size_t)c * HWPIX + px];            \
      r_[2 * cc + 1] = *(const float4*)&f3b[(size_t)(c + 1) * HWPIX + px];      \
    }
    VLOAD(0);
    for (int c0 = 0; c0 < CH; c0 += 64) {
      __syncthreads();
#pragma unroll
      for (int cc = 0; cc < 2; ++cc) {
        const int c = 32 * cc + g2;
#pragma unroll
        for (int i = 0; i < 4; ++i) {
          bf16x2 pk;
          pk[0] = (__bf16)((const float*)&r_[2 * cc])[i];
          pk[1] = (__bf16)((const float*)&r_[2 * cc + 1])[i];
          *(bf16x2*)&f_s[0][(px + i) * FS_STR + c] = pk;
        }
      }
      __syncthreads();
      if (c0 < CH - 64) VLOAD(c0 + 64);
      bf16x8 af[2][2];  // [ct][kh] : W rows (out-ch = 32w + 16ct + q16)
#pragma unroll
      for (int ct = 0; ct < 2; ++ct)
#pragma unroll
        for (int kh = 0; kh < 2; ++kh)
          af[ct][kh] = w_frag(wv + (size_t)(32 * w + 16 * ct + q16) * CH
                              + c0 + 32 * kh + quad * 8);
#pragma unroll
      for (int nt = 0; nt < 8; ++nt) {
#pragma unroll
        for (int kh = 0; kh < 2; ++kh) {
          const bf16x8 bfr =
              ld_frag(&f_s[0][(16 * nt + q16) * FS_STR + 32 * kh + quad * 8]);
#pragma unroll
          for (int ct = 0; ct < 2; ++ct)
            acc[ct][nt] = __builtin_amdgcn_mfma_f32_16x16x32_bf16(
                af[ct][kh], bfr, acc[ct][nt], 0, 0, 0);
        }
      }
    }
#pragma unroll
    for (int ct = 0; ct < 2; ++ct) {
      const float4 bi = *(const float4*)&bv[32 * w + 16 * ct + quad * 4];
#pragma unroll
      for (int nt = 0; nt < 8; ++nt) {
#pragma unroll
        for (int r = 0; r < 4; ++r) {
          const int c = 32 * w + 16 * ct + quad * 4 + r;
          vv[((size_t)b * CH + c) * HWPIX + n0 + 16 * nt + q16] =
              (__bf16)(acc[ct][nt][r] + ((const float*)&bi)[r]);
        }
      }
    }
#undef VLOAD
  }
}

// ---- Pipelined flash attention, 2 key-tiles (128 keys) per barrier region.
// Theory: the 164-us plateau is per-barrier skew/lockstep cost x64 barriers
// (pipe-issue work is only ~2k of the 6.1k cyc/iter). Halving barrier count
// (32 regions) amortizes it. Same total MFMA/LDS/exp work as R1.
// R9 BUGFIX: region stride in kT is 128 keys * 32 el = 4096 elements; the
// failed run used 8192 (256 keys) in the main-loop prefetch -> regions >=2
// read wrong/out-of-range K (absmax 1.88). Prologue already used 4096.
// 8 waves/block (512 thr). grid 512: b = bx&7 (XCD-pinned), q-tile = bx>>3.
// Scores: wave w owns q rows [16*(w&3),+16) x key half (w>>2)*32 of EACH
// 64-key tile, SWAPPED mfma(K,Q). AV: wave w owns out-channels [32w,+32).
// P region: [64 q][128 m] bf16, 256 B rows, byte ^= ((q16&7)<<4) swizzle
// (bits 4-6 only; the tile bit 7 is untouched -> same verified algebra).
__global__ __launch_bounds__(512, 4) void attn_kernel(
    const __bf16* __restrict__ qT, const __bf16* __restrict__ kT,
    const __bf16* __restrict__ vv, float* __restrict__ out)
{
  __shared__ __align__(16) __bf16 p_s[2][64 * 128];  // [q][m], 256 B rows
  __shared__ float L_s[2][64];

  const int t    = threadIdx.x;
  const int w    = __builtin_amdgcn_readfirstlane(t >> 6);
  const int lane = t & 63;
  const int q16  = lane & 15;
  const int quad = lane >> 4;
  const int qb   = w & 3;   // score q-block (16 rows)
  const int hb   = w >> 2;  // score key-half (32 of each 64-key tile)
  const int swz  = (q16 & 7) << 4;

  const int b  = blockIdx.x & 7;
  const int q0 = (blockIdx.x >> 3) * 64;

  const __bf16* kTb = kT + (size_t)b * HWPIX * CQK_;
  // lane offset within a 64-key tile: key = 32*hb + 16*mt + q16, ck = quad*8..+8
  const size_t koff = (size_t)(32 * hb + q16) * CQK_ + quad * 8;

  // running V pointers (advance 128 keys = 256 B per region); ch = 32w+16ct+q16
  const __bf16* vp[2];
#pragma unroll
  for (int ct = 0; ct < 2; ++ct)
    vp[ct] = vv + ((size_t)b * CH + 32 * w + 16 * ct + q16) * HWPIX + quad * 8;

  // Q fragment: q row = q0 + 16*qb + q16 (B-operand in swapped scores)
  const bf16x8 qfrag =
      *(const bf16x8*)(qT + ((size_t)b * HWPIX + q0 + 16 * qb + q16) * CQK_ + quad * 8);

  f32x4 oacc[2][4];
#pragma unroll
  for (int i = 0; i < 2; ++i)
#pragma unroll
    for (int j = 0; j < 4; ++j)
      oacc[i][j] = (f32x4){0.f, 0.f, 0.f, 0.f};
  float Lp = 0.f;  // lane-local partial row-sum (q row 16qb+q16, key-half hb)

  // ---- prologue: scores region 0 (tiles 0,1) -> p_s[0]; kf <- region 1
  // kf index tm = 2*tile + mt
  bf16x8 kf[4];
#pragma unroll
  for (int tm = 0; tm < 4; ++tm)
    kf[tm] = *(const bf16x8*)(kTb + (size_t)(tm >> 1) * 2048 + (tm & 1) * 512 + koff);
  {
    f32x4 Sv[4];
#pragma unroll
    for (int tm = 0; tm < 4; ++tm)
      Sv[tm] = __builtin_amdgcn_mfma_f32_16x16x32_bf16(
          kf[tm], qfrag, (f32x4){0.f, 0.f, 0.f, 0.f}, 0, 0, 0);
    const __bf16* kb1 = kTb + 4096;  // region 1 (128 keys * 32 el)
#pragma unroll
    for (int tm = 0; tm < 4; ++tm)
      kf[tm] = *(const bf16x8*)(kb1 + (size_t)(tm >> 1) * 2048 + (tm & 1) * 512 + koff);
    char* pw = (char*)p_s[0] + (16 * qb + q16) * 256;
#pragma unroll
    for (int tm = 0; tm < 4; ++tm) {
      bf16x4 pk;
#pragma unroll
      for (int r = 0; r < 4; ++r) {
        const float e = __expf(Sv[tm][r]);  // key = 64t + 32hb + 16mt + 4quad + r
        Lp += e;
        pk[r] = (__bf16)e;
      }
      *(bf16x4*)(pw + ((128 * (tm >> 1) + 64 * hb + 32 * (tm & 1) + 8 * quad) ^ swz)) = pk;
    }
  }
  __syncthreads();

  // ---- main loop: region i does AV for tiles 2i,2i+1; scores for region i+1
  for (int i = 0; i < 32; ++i) {
    // V fragments for region i (issued first; consumed after score phase)
    bf16x8 vf[2][4];
#pragma unroll
    for (int ct = 0; ct < 2; ++ct)
#pragma unroll
      for (int mh = 0; mh < 4; ++mh)
        vf[ct][mh] = *(const bf16x8*)(vp[ct] + mh * 32);

    const char* pb = (const char*)p_s[i & 1];

    if (i < 31) {
      // scores for region i+1 (kf prefetched last region), swapped operands
      f32x4 Sv[4];
#pragma unroll
      for (int tm = 0; tm < 4; ++tm)
        Sv[tm] = __builtin_amdgcn_mfma_f32_16x16x32_bf16(
            kf[tm], qfrag, (f32x4){0.f, 0.f, 0.f, 0.f}, 0, 0, 0);
      // prefetch kf for region i+2 (region stride = 4096 elements)
      const __bf16* kb2 = kTb + (size_t)((i + 2) & 31) * 4096;
#pragma unroll
      for (int tm = 0; tm < 4; ++tm)
        kf[tm] = *(const bf16x8*)(kb2 + (size_t)(tm >> 1) * 2048 + (tm & 1) * 512 + koff);
      // exp + packed b64 writes of region i+1 P into the other buffer
      char* pw = (char*)p_s[(i + 1) & 1] + (16 * qb + q16) * 256;
#pragma unroll
      for (int tm = 0; tm < 4; ++tm) {
        bf16x4 pk;
#pragma unroll
        for (int r = 0; r < 4; ++r) {
          const float e = __expf(Sv[tm][r]);
          Lp += e;
          pk[r] = (__bf16)e;
        }
        *(bf16x4*)(pw + ((128 * (tm >> 1) + 64 * hb + 32 * (tm & 1) + 8 * quad) ^ swz)) = pk;
      }
    }

    // AV for region i: per 32-key slice mh, load P then 8 MFMA (bounds VGPR)
#pragma unroll
    for (int mh = 0; mh < 4; ++mh) {
      bf16x8 pf[4];
#pragma unroll
      for (int nt = 0; nt < 4; ++nt)
        pf[nt] = *(const bf16x8*)(pb + (16 * nt + q16) * 256
                                  + ((64 * mh + 16 * quad) ^ swz));
#pragma unroll
      for (int ct = 0; ct < 2; ++ct)
#pragma unroll
        for (int nt = 0; nt < 4; ++nt)
          oacc[ct][nt] = __builtin_amdgcn_mfma_f32_16x16x32_bf16(
              vf[ct][mh], pf[nt], oacc[ct][nt], 0, 0, 0);
    }

#pragma unroll
    for (int ct = 0; ct < 2; ++ct) vp[ct] += 128;
    __syncthreads();
  }

  // ---- finalize L: lane-local partial -> sum over the 4 quads (same q16)
  Lp += __shfl_xor(Lp, 16);
  Lp += __shfl_xor(Lp, 32);
  if (quad == 0) L_s[hb][16 * qb + q16] = Lp;
  __syncthreads();

  float rinv[4];
#pragma unroll
  for (int nt = 0; nt < 4; ++nt)
    rinv[nt] = 1.0f / (L_s[0][16 * nt + q16] + L_s[1][16 * nt + q16]);

  float* ob = out + ((size_t)b * CH + 32 * w) * HWPIX + q0;
#pragma unroll
  for (int ct = 0; ct < 2; ++ct)
#pragma unroll
    for (int r = 0; r < 4; ++r)
#pragma unroll
      for (int nt = 0; nt < 4; ++nt)
        ob[(size_t)(16 * ct + quad * 4 + r) * HWPIX + 16 * nt + q16] =
            oacc[ct][nt][r] * rinv[nt];
}

extern "C" void kernel_launch(void* const* d_in, const int* in_sizes, int n_in,
                              void* d_out, int out_size, void* d_ws, size_t ws_size,
                              hipStream_t stream)
{
  const float* f1 = (const float*)d_in[0];
  const float* f2 = (const float*)d_in[1];
  const float* f3 = (const float*)d_in[2];
  const float* wq = (const float*)d_in[3];
  const float* bq = (const float*)d_in[4];
  const float* wk = (const float*)d_in[5];
  const float* bk = (const float*)d_in[6];
  const float* wv = (const float*)d_in[7];
  const float* bv = (const float*)d_in[8];
  float* outp = (float*)d_out;

  // workspace: qT [8][4096][32] | kT [8][4096][32] | v [8][256][4096]  (bf16, 20 MB)
  __bf16* qTw = (__bf16*)d_ws;
  __bf16* kTw = qTw + (size_t)BATCH * HWPIX * CQK_;
  __bf16* vw  = kTw + (size_t)BATCH * HWPIX * CQK_;

  proj_all<<<dim3(32, 2, 8), 512, 0, stream>>>(f1, f2, f3, wq, bq, wk, bk, wv, bv,
                                               qTw, kTw, vw);
  attn_kernel<<<dim3(512), 512, 0, stream>>>(qTw, kTw, vw, outp);
}

// Round 11
// 293.831 us; speedup vs baseline: 1.1589x; 1.0060x over previous
//
#include <hip/hip_runtime.h>
#include <math.h>

#define BATCH 8
#define CH    256
#define HWPIX 4096
#define CQK_  32

typedef __bf16 bf16x8 __attribute__((ext_vector_type(8)));
typedef __bf16 bf16x4 __attribute__((ext_vector_type(4)));
typedef __bf16 bf16x2 __attribute__((ext_vector_type(2)));
typedef float  f32x4  __attribute__((ext_vector_type(4)));

#define FS_STR 68   // LDS transpose-tile row stride in bf16 (136 B: 8B-aligned)

// load a bf16x8 fragment from LDS as two 8B halves (rows only 8B-aligned)
static __device__ inline bf16x8 ld_frag(const __bf16* p) {
  bf16x4 lo = *(const bf16x4*)p;
  bf16x4 hi = *(const bf16x4*)(p + 4);
  return __builtin_shufflevector(lo, hi, 0, 1, 2, 3, 4, 5, 6, 7);
}

// load 8 consecutive fp32 from a W row, convert to bf16x8 fragment
static __device__ inline bf16x8 w_frag(const float* p) {
  const float4 a = *(const float4*)p;
  const float4 b = *(const float4*)(p + 4);
  bf16x8 r;
  r[0] = (__bf16)a.x; r[1] = (__bf16)a.y; r[2] = (__bf16)a.z; r[3] = (__bf16)a.w;
  r[4] = (__bf16)b.x; r[5] = (__bf16)b.y; r[6] = (__bf16)b.z; r[7] = (__bf16)b.w;
  return r;
}

// ---- Fused projections (R10 version, kept: proj ~75 us, near its 64-us HBM
// floor). 128-pixel tiles -> 512 B DRAM chunks. grid (32, 2, 8), block 512.
__global__ __launch_bounds__(512, 4) void proj_all(
    const float* __restrict__ f1, const float* __restrict__ f2,
    const float* __restrict__ f3,
    const float* __restrict__ wq, const float* __restrict__ bq,
    const float* __restrict__ wk, const float* __restrict__ bk,
    const float* __restrict__ wv, const float* __restrict__ bv,
    __bf16* __restrict__ qT, __bf16* __restrict__ kT, __bf16* __restrict__ vv)
{
  __shared__ __align__(16) __bf16 f_s[2][128 * FS_STR];  // [px][cin] transposed
  const int t    = threadIdx.x;
  const int w    = __builtin_amdgcn_readfirstlane(t >> 6);
  const int lane = t & 63;
  const int q16  = lane & 15;
  const int quad = lane >> 4;
  const int b    = blockIdx.z;
  const int n0   = blockIdx.x * 128;
  const int mode = blockIdx.y;

  if (mode == 0) {
    const int half = t >> 8;          // 0: f1/Q staging, 1: f2/K staging
    const int th   = t & 255;
    const int px   = (th & 31) * 4;   // pixel 0..124 -> 32 thr x float4 = 512 B/ch
    const int g2   = (th >> 5) * 2;   // channel-pair base 0..14
    const int isK  = w >> 2;          // waves 0-3: Q, 4-7: K
    const int qr   = w & 3;           // 32-pixel row group

    const float* fsrc = (half ? f2 : f1) + (size_t)b * CH * HWPIX + n0;
    __bf16* fdst = f_s[half];
    const float* wmat = isK ? wk : wq;

    f32x4 acc[2][2];  // [ot][rg]
#pragma unroll
    for (int i = 0; i < 2; ++i)
#pragma unroll
      for (int j = 0; j < 2; ++j) acc[i][j] = (f32x4){0.f, 0.f, 0.f, 0.f};

    float4 rg_[8];
#define PLOAD(c0)                                                               \
    _Pragma("unroll") for (int cc = 0; cc < 4; ++cc) {                          \
      const int c = (c0) + 16 * cc + g2;                                        \
      rg_[2 * cc]     = *(const float4*)&fsrc[(size_t)c * HWPIX + px];          \
      rg_[2 * cc + 1] = *(const float4*)&fsrc[(size_t)(c + 1) * HWPIX + px];    \
    }
    PLOAD(0);
    for (int c0 = 0; c0 < CH; c0 += 64) {
      __syncthreads();  // previous iter's readers done; LDS reusable
#pragma unroll
      for (int cc = 0; cc < 4; ++cc) {
        const int c = 16 * cc + g2;
#pragma unroll
        for (int i = 0; i < 4; ++i) {
          bf16x2 pk;
          pk[0] = (__bf16)((const float*)&rg_[2 * cc])[i];
          pk[1] = (__bf16)((const float*)&rg_[2 * cc + 1])[i];
          *(bf16x2*)&fdst[(px + i) * FS_STR + c] = pk;
        }
      }
      __syncthreads();
      if (c0 < CH - 64) PLOAD(c0 + 64);  // prefetch; hides under compute
      bf16x8 af[2][2];  // [rg][kh]
#pragma unroll
      for (int rg = 0; rg < 2; ++rg)
#pragma unroll
        for (int kh = 0; kh < 2; ++kh)
          af[rg][kh] = ld_frag(&f_s[isK][(32 * qr + 16 * rg + q16) * FS_STR
                                         + 32 * kh + quad * 8]);
#pragma unroll
      for (int ot = 0; ot < 2; ++ot)
#pragma unroll
        for (int kh = 0; kh < 2; ++kh) {
          const bf16x8 wf =
              w_frag(wmat + (size_t)(16 * ot + q16) * CH + c0 + 32 * kh + quad * 8);
#pragma unroll
          for (int rg = 0; rg < 2; ++rg)
            acc[ot][rg] = __builtin_amdgcn_mfma_f32_16x16x32_bf16(
                af[rg][kh], wf, acc[ot][rg], 0, 0, 0);
        }
    }
    const float* bias = isK ? bk : bq;
    __bf16* outT = isK ? kT : qT;
    const float b0 = bias[q16], b1 = bias[16 + q16];
#pragma unroll
    for (int rg = 0; rg < 2; ++rg)
#pragma unroll
      for (int r = 0; r < 4; ++r) {
        const size_t row = (size_t)b * HWPIX + n0 + 32 * qr + 16 * rg + quad * 4 + r;
        outT[row * CQK_ + q16]      = (__bf16)(acc[0][rg][r] + b0);
        outT[row * CQK_ + 16 + q16] = (__bf16)(acc[1][rg][r] + b1);
      }
#undef PLOAD
  } else {
    // ---- V: stage 128x64 f3 c-tile once; 256 out-ch, 32 per wave.
    const int px = (t & 31) * 4;
    const int g2 = (t >> 5) * 2;   // channel-pair base 0..30
    const float* f3b = f3 + (size_t)b * CH * HWPIX + n0;

    f32x4 acc[2][8];  // [ct][nt]
#pragma unroll
    for (int ct = 0; ct < 2; ++ct)
#pragma unroll
      for (int nt = 0; nt < 8; ++nt) acc[ct][nt] = (f32x4){0.f, 0.f, 0.f, 0.f};

    float4 r_[4];
#define VLOAD(c0)                                                               \
    _Pragma("unroll") for (int cc = 0; cc < 2; ++cc) {                          \
      const int c = (c0) + 32 * cc + g2;                                        \
      r_[2 * cc]     = *(const float4*)&f3b[(size_t)c * HWPIX + px];            \
      r_[2 * cc + 1] = *(const float4*)&f3b[(size_t)(c + 1) * HWPIX + px];      \
    }
    VLOAD(0);
    for (int c0 = 0; c0 < CH; c0 += 64) {
      __syncthreads();
#pragma unroll
      for (int cc = 0; cc < 2; ++cc) {
        const int c = 32 * cc + g2;
#pragma unroll
        for (int i = 0; i < 4; ++i) {
          bf16x2 pk;
          pk[0] = (__bf16)((const float*)&r_[2 * cc])[i];
          pk[1] = (__bf16)((const float*)&r_[2 * cc + 1])[i];
          *(bf16x2*)&f_s[0][(px + i) * FS_STR + c] = pk;
        }
      }
      __syncthreads();
      if (c0 < CH - 64) VLOAD(c0 + 64);
      bf16x8 af[2][2];  // [ct][kh] : W rows (out-ch = 32w + 16ct + q16)
#pragma unroll
      for (int ct = 0; ct < 2; ++ct)
#pragma unroll
        for (int kh = 0; kh < 2; ++kh)
          af[ct][kh] = w_frag(wv + (size_t)(32 * w + 16 * ct + q16) * CH
                              + c0 + 32 * kh + quad * 8);
#pragma unroll
      for (int nt = 0; nt < 8; ++nt) {
#pragma unroll
        for (int kh = 0; kh < 2; ++kh) {
          const bf16x8 bfr =
              ld_frag(&f_s[0][(16 * nt + q16) * FS_STR + 32 * kh + quad * 8]);
#pragma unroll
          for (int ct = 0; ct < 2; ++ct)
            acc[ct][nt] = __builtin_amdgcn_mfma_f32_16x16x32_bf16(
                af[ct][kh], bfr, acc[ct][nt], 0, 0, 0);
        }
      }
    }
#pragma unroll
    for (int ct = 0; ct < 2; ++ct) {
      const float4 bi = *(const float4*)&bv[32 * w + 16 * ct + quad * 4];
#pragma unroll
      for (int nt = 0; nt < 8; ++nt) {
#pragma unroll
        for (int r = 0; r < 4; ++r) {
          const int c = 32 * w + 16 * ct + quad * 4 + r;
          vv[((size_t)b * CH + c) * HWPIX + n0 + 16 * nt + q16] =
              (__bf16)(acc[ct][nt][r] + ((const float*)&bi)[r]);
        }
      }
    }
#undef VLOAD
  }
}

// ---- Pipelined flash attention: R4 64-key structure + PHASE-STAGGERED start.
// Resonance theory: the 164-us plateau = per-CU phase lockstep. Each CU hosts
// exactly 2 identical blocks; both sit in the exp/score phase (trans busy,
// LDS idle) then both in AV (LDS busy, trans idle) -> per-tile time is the
// SUM of phase costs (~5.7k cyc, matches measured 6.1k) instead of the max
// (~2.8k). Fix: block processes key-tiles in rotated order (i + qtile) & 63 —
// order is math-irrelevant (softmax here is a pure sum, no running max), K/V
// stay XCD-pinned L2-resident, but co-resident blocks (q-tiles k, k+32) now
// run 32 tiles out of phase -> score phase of one overlaps AV of the other.
// 8 waves/block (512 thr). grid 512: b = bx&7 (XCD-pinned), q-tile = bx>>3.
// Scores: wave w owns q rows [16*(w&3),+16) x key half (w>>2)*32, SWAPPED
// mfma(K,Q). AV: wave w owns out-channels [32w,+32).
// P tile: [64 q][64 m] bf16, 128 B rows, byte ^= ((q16&7)<<4) XOR swizzle.
__global__ __launch_bounds__(512, 4) void attn_kernel(
    const __bf16* __restrict__ qT, const __bf16* __restrict__ kT,
    const __bf16* __restrict__ vv, float* __restrict__ out)
{
  __shared__ __align__(16) __bf16 p_s[2][64 * 64];  // [q][m], stride 64 bf16 = 128 B
  __shared__ float L_s[2][64];

  const int t    = threadIdx.x;
  const int w    = __builtin_amdgcn_readfirstlane(t >> 6);
  const int lane = t & 63;
  const int q16  = lane & 15;
  const int quad = lane >> 4;
  const int qb   = w & 3;   // score q-block (16 rows)
  const int hb   = w >> 2;  // score m-half (32 of 64 keys)
  const int swz  = (q16 & 7) << 4;

  const int b    = blockIdx.x & 7;
  const int qt   = blockIdx.x >> 3;   // q-tile index 0..63
  const int q0   = qt * 64;
  const int ioff = qt & 63;           // key-tile rotation (phase stagger)

  const __bf16* kTb = kT + (size_t)b * HWPIX * CQK_;
  // lane offset within a 64-key K tile: key = 32*hb + 16*mt + q16, ck = quad*8..+8
  const size_t koff = (size_t)(32 * hb + q16) * CQK_ + quad * 8;

  // V base pointers (key index added per iteration); ch = 32w + 16ct + q16
  const __bf16* vb[2];
#pragma unroll
  for (int ct = 0; ct < 2; ++ct)
    vb[ct] = vv + ((size_t)b * CH + 32 * w + 16 * ct + q16) * HWPIX + quad * 8;

  // Q fragment: q row = q0 + 16*qb + q16 (B-operand in swapped scores)
  const bf16x8 qfrag =
      *(const bf16x8*)(qT + ((size_t)b * HWPIX + q0 + 16 * qb + q16) * CQK_ + quad * 8);

  f32x4 oacc[2][4];
#pragma unroll
  for (int i = 0; i < 2; ++i)
#pragma unroll
    for (int j = 0; j < 4; ++j)
      oacc[i][j] = (f32x4){0.f, 0.f, 0.f, 0.f};
  float Lp = 0.f;  // lane-local partial row-sum (q row 16qb+q16, m-half hb)

  // ---- prologue: scores for tile ioff -> p_s[0]; kf <- tile ioff+1
  bf16x8 kf[2];
#pragma unroll
  for (int mt = 0; mt < 2; ++mt)
    kf[mt] = *(const bf16x8*)(kTb + (size_t)ioff * (64 * CQK_) + koff + mt * 512);
  {
    f32x4 Sv[2];
#pragma unroll
    for (int mt = 0; mt < 2; ++mt)
      Sv[mt] = __builtin_amdgcn_mfma_f32_16x16x32_bf16(
          kf[mt], qfrag, (f32x4){0.f, 0.f, 0.f, 0.f}, 0, 0, 0);
    const __bf16* kb1 = kTb + (size_t)((ioff + 1) & 63) * (64 * CQK_);
#pragma unroll
    for (int mt = 0; mt < 2; ++mt)
      kf[mt] = *(const bf16x8*)(kb1 + koff + mt * 512);
    char* pw = (char*)p_s[0] + (16 * qb + q16) * 128;
#pragma unroll
    for (int mt = 0; mt < 2; ++mt) {
      bf16x4 pk;
#pragma unroll
      for (int r = 0; r < 4; ++r) {
        const float e = __expf(Sv[mt][r]);  // key = 32hb + 16mt + 4quad + r
        Lp += e;
        pk[r] = (__bf16)e;
      }
      *(bf16x4*)(pw + ((64 * hb + 32 * mt + 8 * quad) ^ swz)) = pk;
    }
  }
  __syncthreads();

  // ---- main loop: iter i: AV for tile (i+ioff)&63; scores for (i+1+ioff)&63
  for (int i = 0; i < 64; ++i) {
    const int jj = (i + ioff) & 63;  // logical key tile this iteration

    // V fragments for tile jj (issued first; consumed after score/exp phase)
    bf16x8 vf[2][2];
#pragma unroll
    for (int ct = 0; ct < 2; ++ct)
#pragma unroll
      for (int mh = 0; mh < 2; ++mh)
        vf[ct][mh] = *(const bf16x8*)(vb[ct] + jj * 64 + mh * 32);

    // P fragments for tile jj (swizzled reads; all 64 q rows)
    const char* pb = (const char*)p_s[i & 1];
    bf16x8 pf[4][2];
#pragma unroll
    for (int nt = 0; nt < 4; ++nt)
#pragma unroll
      for (int mh = 0; mh < 2; ++mh)
        pf[nt][mh] = *(const bf16x8*)(pb + (16 * nt + q16) * 128
                                      + ((64 * mh + 16 * quad) ^ swz));

    if (i < 63) {
      // scores for tile (i+1+ioff)&63 (kf prefetched last iter), swapped
      f32x4 Sv[2];
#pragma unroll
      for (int mt = 0; mt < 2; ++mt)
        Sv[mt] = __builtin_amdgcn_mfma_f32_16x16x32_bf16(
            kf[mt], qfrag, (f32x4){0.f, 0.f, 0.f, 0.f}, 0, 0, 0);
      // prefetch kf for tile (i+2+ioff)&63
      const __bf16* kb2 = kTb + (size_t)((i + 2 + ioff) & 63) * (64 * CQK_);
#pragma unroll
      for (int mt = 0; mt < 2; ++mt)
        kf[mt] = *(const bf16x8*)(kb2 + koff + mt * 512);
      // exp + packed b64 write of next P into the other buffer
      char* pw = (char*)p_s[(i + 1) & 1] + (16 * qb + q16) * 128;
#pragma unroll
      for (int mt = 0; mt < 2; ++mt) {
        bf16x4 pk;
#pragma unroll
        for (int r = 0; r < 4; ++r) {
          const float e = __expf(Sv[mt][r]);
          Lp += e;
          pk[r] = (__bf16)e;
        }
        *(bf16x4*)(pw + ((64 * hb + 32 * mt + 8 * quad) ^ swz)) = pk;
      }
    }

    // AV for tile jj: O[ch = 32w+16ct+...][q = 16nt+...] += V * P
#pragma unroll
    for (int ct = 0; ct < 2; ++ct)
#pragma unroll
      for (int nt = 0; nt < 4; ++nt)
#pragma unroll
        for (int mh = 0; mh < 2; ++mh)
          oacc[ct][nt] = __builtin_amdgcn_mfma_f32_16x16x32_bf16(
              vf[ct][mh], pf[nt][mh], oacc[ct][nt], 0, 0, 0);

    __syncthreads();
  }

  // ---- finalize L: lane-local partial -> sum over the 4 quads (same q16)
  Lp += __shfl_xor(Lp, 16);
  Lp += __shfl_xor(Lp, 32);
  if (quad == 0) L_s[hb][16 * qb + q16] = Lp;
  __syncthreads();

  float rinv[4];
#pragma unroll
  for (int nt = 0; nt < 4; ++nt)
    rinv[nt] = 1.0f / (L_s[0][16 * nt + q16] + L_s[1][16 * nt + q16]);

  float* ob = out + ((size_t)b * CH + 32 * w) * HWPIX + q0;
#pragma unroll
  for (int ct = 0; ct < 2; ++ct)
#pragma unroll
    for (int r = 0; r < 4; ++r)
#pragma unroll
      for (int nt = 0; nt < 4; ++nt)
        ob[(size_t)(16 * ct + quad * 4 + r) * HWPIX + 16 * nt + q16] =
            oacc[ct][nt][r] * rinv[nt];
}

extern "C" void kernel_launch(void* const* d_in, const int* in_sizes, int n_in,
                              void* d_out, int out_size, void* d_ws, size_t ws_size,
                              hipStream_t stream)
{
  const float* f1 = (const float*)d_in[0];
  const float* f2 = (const float*)d_in[1];
  const float* f3 = (const float*)d_in[2];
  const float* wq = (const float*)d_in[3];
  const float* bq = (const float*)d_in[4];
  const float* wk = (const float*)d_in[5];
  const float* bk = (const float*)d_in[6];
  const float* wv = (const float*)d_in[7];
  const float* bv = (const float*)d_in[8];
  float* outp = (float*)d_out;

  // workspace: qT [8][4096][32] | kT [8][4096][32] | v [8][256][4096]  (bf16, 20 MB)
  __bf16* qTw = (__bf16*)d_ws;
  __bf16* kTw = qTw + (size_t)BATCH * HWPIX * CQK_;
  __bf16* vw  = kTw + (size_t)BATCH * HWPIX * CQK_;

  proj_all<<<dim3(32, 2, 8), 512, 0, stream>>>(f1, f2, f3, wq, bq, wk, bk, wv, bv,
                                               qTw, kTw, vw);
  attn_kernel<<<dim3(512), 512, 0, stream>>>(qTw, kTw, vw, outp);
}